// Round 4
// baseline (5416.880 us; speedup 1.0000x reference)
//
#include <hip/hip_runtime.h>
#include <math.h>

#define BB 4
#define NN 512
#define EE 128
#define NODE_F 16
#define EDGE_F 8
#define LL 3

typedef float vf4 __attribute__((ext_vector_type(4)));

__global__ __launch_bounds__(512, 8) void k_rows(
    const float* __restrict__ nf,          // B,N,16
    const float* __restrict__ ef,          // B,N,N,8
    const float* __restrict__ W,           // B,N,N
    const int*   __restrict__ assigned,    // B,N
    const int*   __restrict__ open_group,  // B,N
    const int*   __restrict__ action_mask, // B,N
    const float* __restrict__ build_limit, // B,3
    const float* __restrict__ open_group_size, // B,3
    const float* __restrict__ embed_w,     // 22,128
    const float* __restrict__ embed_b,     // 128
    const float* __restrict__ node_w,      // L,128,128
    const float* __restrict__ edge_w,      // L,8,128
    const float* __restrict__ weight_w,    // L,128
    const float* __restrict__ out_w,       // L,128,128
    const float* __restrict__ out_b,       // L,128
    float* __restrict__ hout)              // B*N,128
{
    const int i   = blockIdx.x;
    const int b   = blockIdx.y;
    const int t   = threadIdx.x;
    const int e   = t & 127;
    const int js  = t >> 7;          // 0..3
    const int row = b * NN + i;

    __shared__ __align__(16) float efsh[NN * EDGE_F]; // 16 KB
    __shared__ __align__(16) float wsh[NN];           // 2 KB
    __shared__ float hsh[EE];
    __shared__ float hipart[4][EE];
    __shared__ float aggsh[4][EE];
    __shared__ float aggfin[EE];
    __shared__ float opart[4][EE];
    __shared__ float xsh[24];

    // ---- stage ef row + W row into LDS ----
    {
        const float4* ef4 = (const float4*)(ef + (size_t)row * NN * EDGE_F);
        float4* es4 = (float4*)efsh;
        es4[t]       = ef4[t];
        es4[t + 512] = ef4[t + 512];
        wsh[t]       = W[(size_t)row * NN + t];
    }

    // ---- x = [node_features(16), assigned, open, mask, ratio(3)] ----
    if (t < NODE_F) {
        xsh[t] = nf[row * NODE_F + t];
    } else if (t == 16) {
        xsh[16] = assigned[row] ? 1.0f : 0.0f;
    } else if (t == 17) {
        xsh[17] = open_group[row] ? 1.0f : 0.0f;
    } else if (t == 18) {
        xsh[18] = action_mask[row] ? 1.0f : 0.0f;
    } else if (t < 22) {
        int k = t - 19;
        xsh[t] = open_group_size[b * 3 + k] / fmaxf(build_limit[b * 3 + k], 1e-6f);
    }
    __syncthreads();

    // ---- h0 = x @ embed_w + embed_b ----
    if (t < EE) {
        float h0 = embed_b[e];
        #pragma unroll
        for (int k = 0; k < 22; ++k)
            h0 = fmaf(xsh[k], embed_w[k * EE + e], h0);
        hsh[e] = h0;
    }

    const float c  = 2.8853900817779268f;  // 2*log2(e) folded into tanh arg
    const int  j0 = js * 128;
    const int  k0 = js * 32;

    for (int l = 0; l < LL; ++l) {
        __syncthreads();   // B1: hsh stable

        // ---- hi partial: k in [k0,k0+32) over node_w column e ----
        const float* nw = node_w + l * EE * EE + k0 * EE + e;
        float hp = 0.0f;
        #pragma unroll 8
        for (int k = 0; k < 32; ++k)
            hp = fmaf(hsh[k0 + k], nw[k * EE], hp);
        hipart[js][e] = hp;
        __syncthreads();   // B2

        const float hi = c * (hipart[0][e] + hipart[1][e] + hipart[2][e] + hipart[3][e]);

        const float* ew = edge_w + l * EDGE_F * EE + e;
        const float we0 = c * ew[0 * EE];
        const float we1 = c * ew[1 * EE];
        const float we2 = c * ew[2 * EE];
        const float we3 = c * ew[3 * EE];
        const float we4 = c * ew[4 * EE];
        const float we5 = c * ew[5 * EE];
        const float we6 = c * ew[6 * EE];
        const float we7 = c * ew[7 * EE];
        const float wl  = c * weight_w[l * EE + e];

        // ---- j loop: 32 groups of 4, register-batched loads then 4 chains ----
        float rs0 = 0.0f, rs1 = 0.0f;
        const vf4* e4 = (const vf4*)&efsh[j0 * 8];
        const vf4* w4 = (const vf4*)&wsh[j0];

        #define CHAIN(_a, _b, _w, _r)                                        \
            { float _u = fmaf(_a.x, we0, hi);                                \
              _u = fmaf(_a.y, we1, _u);                                      \
              _u = fmaf(_a.z, we2, _u);                                      \
              _u = fmaf(_a.w, we3, _u);                                      \
              _u = fmaf(_w, wl, _u);                                         \
              float _v = _b.x * we4;                                         \
              _v = fmaf(_b.y, we5, _v);                                      \
              _v = fmaf(_b.z, we6, _v);                                      \
              _v = fmaf(_b.w, we7, _v);                                      \
              float _ex = __builtin_amdgcn_exp2f(_u + _v);                   \
              _r = __builtin_amdgcn_rcpf(_ex + 1.0f); }

        #pragma unroll
        for (int g = 0; g < 32; ++g) {
            vf4 a0 = e4[g * 8 + 0], b0 = e4[g * 8 + 1];
            vf4 a1 = e4[g * 8 + 2], b1 = e4[g * 8 + 3];
            vf4 a2 = e4[g * 8 + 4], b2 = e4[g * 8 + 5];
            vf4 a3 = e4[g * 8 + 6], b3 = e4[g * 8 + 7];
            vf4 wv = w4[g];
            float r0, r1, r2, r3;
            CHAIN(a0, b0, wv.x, r0);
            CHAIN(a1, b1, wv.y, r1);
            CHAIN(a2, b2, wv.z, r2);
            CHAIN(a3, b3, wv.w, r3);
            rs0 += r0 + r2;
            rs1 += r1 + r3;
        }
        #undef CHAIN

        aggsh[js][e] = rs0 + rs1;
        __syncthreads();   // B3

        if (js == 0)
            aggfin[e] = 1.0f - (aggsh[0][e] + aggsh[1][e] + aggsh[2][e] + aggsh[3][e])
                               * (1.0f / 256.0f);
        __syncthreads();   // B4

        // ---- out partial: k in [k0,k0+32) over out_w column e ----
        const float* ow = out_w + l * EE * EE + k0 * EE + e;
        float op = 0.0f;
        #pragma unroll 8
        for (int k = 0; k < 32; ++k)
            op = fmaf(aggfin[k0 + k], ow[k * EE], op);
        opart[js][e] = op;
        __syncthreads();   // B5

        if (js == 0) {
            hsh[e] = hsh[e] + out_b[l * EE + e]
                   + opart[0][e] + opart[1][e] + opart[2][e] + opart[3][e];
        }
        // next-iteration B1 (or final sync below) protects readers
    }

    __syncthreads();
    if (js == 0) hout[(size_t)row * EE + e] = hsh[e];
}

__global__ __launch_bounds__(1024) void k_tail(
    const float* __restrict__ hbuf,        // B*N,128
    const int*   __restrict__ open_group,  // B,N
    const float* __restrict__ context_w,   // 128,128
    const float* __restrict__ key_w,       // 128,128
    const int*   __restrict__ action_mask, // B,N
    const float* __restrict__ logit_bias,  // 1
    float* __restrict__ out)               // B,N
{
    const int b = blockIdx.x;
    const int t = threadIdx.x;
    const int e = t & 127;
    const int s = t >> 7;                  // 0..7

    __shared__ float gmsh[8][EE];
    __shared__ float cntsh[8];
    __shared__ float csh[EE];
    __shared__ float qsh[EE];
    __shared__ float qksh[EE];

    const float* hb = hbuf + (size_t)b * NN * EE;

    // masked group-sum over n, 8-way split
    float gm = 0.0f, cnt = 0.0f;
    const int n0 = s * 64;
    #pragma unroll 4
    for (int u = 0; u < 64; ++u) {
        const int n = n0 + u;
        const float m = (float)open_group[b * NN + n];
        gm = fmaf(m, hb[(size_t)n * EE + e], gm);
        cnt += m;
    }
    gmsh[s][e] = gm;
    if (e == 0) cntsh[s] = cnt;
    __syncthreads();

    if (s == 0) {
        float ca = 0.0f, ga = 0.0f;
        #pragma unroll
        for (int u = 0; u < 8; ++u) { ca += cntsh[u]; ga += gmsh[u][e]; }
        csh[e] = (ca > 0.0f) ? (ga / fmaxf(ca, 1.0f)) : hb[e];  // hb[e]=h[b,0,e]
    }
    __syncthreads();

    if (s == 0) {
        float q = 0.0f;
        #pragma unroll 8
        for (int k = 0; k < EE; ++k)
            q = fmaf(csh[k], context_w[k * EE + e], q);
        qsh[e] = q;
    }
    __syncthreads();

    if (s == 0) {
        float acc = 0.0f;
        const float* kr = key_w + e * EE;   // qk[e] = key_w[e,:] . q
        #pragma unroll 8
        for (int k = 0; k < EE; ++k)
            acc = fmaf(kr[k], qsh[k], acc);
        qksh[e] = acc;
    }
    __syncthreads();

    // ---- logits: 16 waves x 32 rows each ----
    const int wid  = t >> 6;               // 0..15
    const int lane = t & 63;
    const float lb = logit_bias[0];

    for (int r = wid; r < NN; r += 16) {
        const float* hr = hb + (size_t)r * EE;
        float p = hr[lane] * qksh[lane] + hr[lane + 64] * qksh[lane + 64];
        #pragma unroll
        for (int off = 32; off; off >>= 1)
            p += __shfl_down(p, off);
        if (lane == 0) {
            float v = fmaf(p, 0.08838834764831845f, lb);   // /sqrt(128)
            out[b * NN + r] = action_mask[b * NN + r] ? v : -1000000000.0f;
        }
    }
}

extern "C" void kernel_launch(void* const* d_in, const int* in_sizes, int n_in,
                              void* d_out, int out_size, void* d_ws, size_t ws_size,
                              hipStream_t stream) {
    const float* nf         = (const float*)d_in[0];
    const float* ef         = (const float*)d_in[1];
    const float* W          = (const float*)d_in[2];
    const int*   assigned   = (const int*)d_in[3];
    const int*   open_group = (const int*)d_in[4];
    const int*   action_mask= (const int*)d_in[5];
    const float* build_limit= (const float*)d_in[6];
    const float* og_size    = (const float*)d_in[7];
    const float* embed_w    = (const float*)d_in[8];
    const float* embed_b    = (const float*)d_in[9];
    const float* node_w     = (const float*)d_in[10];
    const float* edge_w     = (const float*)d_in[11];
    const float* weight_w   = (const float*)d_in[12];
    const float* out_w      = (const float*)d_in[13];
    const float* out_b      = (const float*)d_in[14];
    const float* context_w  = (const float*)d_in[15];
    const float* key_w      = (const float*)d_in[16];
    const float* logit_bias = (const float*)d_in[17];

    float* hbuf = (float*)d_ws;                       // B*N*E floats = 1 MB

    dim3 grid_rows(NN, BB, 1);
    k_rows<<<grid_rows, 512, 0, stream>>>(nf, ef, W, assigned, open_group,
        action_mask, build_limit, og_size, embed_w, embed_b, node_w, edge_w,
        weight_w, out_w, out_b, hbuf);

    k_tail<<<BB, 1024, 0, stream>>>(hbuf, open_group, context_w, key_w,
        action_mask, logit_bias, (float*)d_out);
}

// Round 6
// 243.177 us; speedup vs baseline: 22.2754x; 22.2754x over previous
//
#include <hip/hip_runtime.h>
#include <math.h>

#define BB 4
#define NN 512
#define EE 128
#define NODE_F 16
#define EDGE_F 8
#define LL 3

typedef __attribute__((ext_vector_type(8))) short bf16x8;
typedef __attribute__((ext_vector_type(4))) float f32x4;

__device__ __forceinline__ ushort bf_hi(float x) {
    uint u = __float_as_uint(x);
    return (ushort)((u + 0x7fffu + ((u >> 16) & 1u)) >> 16);
}
__device__ __forceinline__ float bf_f(ushort h) {
    return __uint_as_float(((uint)h) << 16);
}

__global__ __launch_bounds__(512) void k_rows(
    const float* __restrict__ nf,          // B,N,16
    const float* __restrict__ ef,          // B,N,N,8
    const float* __restrict__ W,           // B,N,N
    const int*   __restrict__ assigned,    // B,N
    const int*   __restrict__ open_group,  // B,N
    const int*   __restrict__ action_mask, // B,N
    const float* __restrict__ build_limit, // B,3
    const float* __restrict__ open_group_size, // B,3
    const float* __restrict__ embed_w,     // 22,128
    const float* __restrict__ embed_b,     // 128
    const float* __restrict__ node_w,      // L,128,128
    const float* __restrict__ edge_w,      // L,8,128
    const float* __restrict__ weight_w,    // L,128
    const float* __restrict__ out_w,       // L,128,128
    const float* __restrict__ out_b,       // L,128
    float* __restrict__ hout)              // B*N,128
{
    const int i   = blockIdx.x;
    const int b   = blockIdx.y;
    const int t   = threadIdx.x;
    const int l   = t & 63;                // lane
    const int w   = t >> 6;                // wave 0..7 -> e-tile
    const int row = b * NN + i;

    // A-fragments: [32 j-tiles][64 lanes] x 8 bf16 = 32 KB
    __shared__ bf16x8 afr[32 * 64];
    __shared__ float hsh[EE];
    __shared__ float hish[EE];
    __shared__ float aggfin[EE];
    __shared__ float xsh[24];

    // ---- x = [node_features(16), assigned, open, mask, ratio(3)] ----
    if (t < NODE_F) {
        xsh[t] = nf[row * NODE_F + t];
    } else if (t == 16) {
        xsh[16] = assigned[row] ? 1.0f : 0.0f;
    } else if (t == 17) {
        xsh[17] = open_group[row] ? 1.0f : 0.0f;
    } else if (t == 18) {
        xsh[18] = action_mask[row] ? 1.0f : 0.0f;
    } else if (t < 22) {
        int k = t - 19;
        xsh[t] = open_group_size[b * 3 + k] / fmaxf(build_limit[b * 3 + k], 1e-6f);
    }

    // ---- pack A-fragments (once; layer-invariant) ----
    // K slots: 0-7: ef_hi  8-15: ef_hi  16-23: ef_lo  24: W_hi 25: W_hi 26: W_lo
    // lane ll of tile jt holds A[j = jt*16 + (ll&15), k = (ll>>4)*8 .. +8]
    {
        const float* efr = ef + (size_t)row * NN * EDGE_F;
        const float* Wr  = W + (size_t)row * NN;
        #pragma unroll
        for (int q = 0; q < 4; ++q) {
            const int eid = t + 512 * q;        // 0..2047
            const int ll  = eid & 63;
            const int jt  = eid >> 6;
            const int g   = ll >> 4;
            const int jj  = jt * 16 + (ll & 15);
            bf16x8 frag;
            if (g < 3) {
                const float4 a = *(const float4*)&efr[jj * 8];
                const float4 c4 = *(const float4*)&efr[jj * 8 + 4];
                float v[8] = {a.x, a.y, a.z, a.w, c4.x, c4.y, c4.z, c4.w};
                if (g < 2) {
                    #pragma unroll
                    for (int m = 0; m < 8; ++m) frag[m] = (short)bf_hi(v[m]);
                } else {
                    #pragma unroll
                    for (int m = 0; m < 8; ++m) {
                        ushort h = bf_hi(v[m]);
                        frag[m] = (short)bf_hi(v[m] - bf_f(h));
                    }
                }
            } else {
                float wv = Wr[jj];
                ushort h = bf_hi(wv);
                ushort lo = bf_hi(wv - bf_f(h));
                frag = (bf16x8){(short)h, (short)h, (short)lo, 0, 0, 0, 0, 0};
            }
            afr[eid] = frag;
        }
    }
    __syncthreads();

    // ---- h0 = x @ embed_w + embed_b ----
    if (t < EE) {
        float h0 = embed_b[t];
        #pragma unroll
        for (int k = 0; k < 22; ++k)
            h0 = fmaf(xsh[k], embed_w[k * EE + t], h0);
        hsh[t] = h0;
    }

    const float c  = 2.8853900817779268f;  // 2*log2(e) folded into weights
    const int  le  = l & 15;
    const int  g   = l >> 4;
    const int  eN  = w * 16 + le;          // this lane's e column

    for (int lay = 0; lay < LL; ++lay) {
        __syncthreads();   // hsh stable

        // ---- hi[e] = c * (h @ node_w[lay])  -- waves 0,1 only ----
        if (t < EE) {
            const float* nw = node_w + lay * EE * EE + t;
            float hp = 0.0f;
            #pragma unroll 8
            for (int k = 0; k < EE; ++k)
                hp = fmaf(hsh[k], nw[k * EE], hp);
            hish[t] = c * hp;
        }

        // ---- B-fragment for this lane (fixed per layer) ----
        // B[k = g*8+m, n = le]:  g0: we_hi  g1: we_lo  g2: we_hi  g3: [wl_hi, wl_lo, wl_hi, 0..]
        bf16x8 bfrag;
        if (g == 3) {
            float x = c * weight_w[lay * EE + eN];
            ushort h = bf_hi(x);
            ushort lo = bf_hi(x - bf_f(h));
            bfrag = (bf16x8){(short)h, (short)lo, (short)h, 0, 0, 0, 0, 0};
        } else {
            const float* ewp = edge_w + lay * EDGE_F * EE + eN;
            if (g == 1) {
                #pragma unroll
                for (int m = 0; m < 8; ++m) {
                    float x = c * ewp[m * EE];
                    ushort h = bf_hi(x);
                    bfrag[m] = (short)bf_hi(x - bf_f(h));
                }
            } else {
                #pragma unroll
                for (int m = 0; m < 8; ++m)
                    bfrag[m] = (short)bf_hi(c * ewp[m * EE]);
            }
        }
        __syncthreads();   // hish ready

        const float hq = hish[eN];
        const f32x4 cin = {hq, hq, hq, hq};

        // ---- 32 j-tiles: MFMA + tanh-accumulate ----
        f32x4 rsum = {0.0f, 0.0f, 0.0f, 0.0f};
        #pragma unroll 4
        for (int jt = 0; jt < 32; ++jt) {
            bf16x8 a = afr[jt * 64 + l];
            f32x4 acc = __builtin_amdgcn_mfma_f32_16x16x32_bf16(a, bfrag, cin, 0, 0, 0);
            #pragma unroll
            for (int r = 0; r < 4; ++r) {
                float ex = __builtin_amdgcn_exp2f(acc[r]);
                rsum[r] += __builtin_amdgcn_rcpf(ex + 1.0f);
            }
        }
        float s = (rsum[0] + rsum[1]) + (rsum[2] + rsum[3]);
        s += __shfl_xor(s, 16);
        s += __shfl_xor(s, 32);
        if (l < 16)
            aggfin[w * 16 + le] = 1.0f - s * (1.0f / 256.0f);
        __syncthreads();   // aggfin ready

        // ---- h += agg @ out_w[lay] + out_b[lay]  -- waves 0,1 only ----
        if (t < EE) {
            const float* ow = out_w + lay * EE * EE + t;
            float hn = hsh[t] + out_b[lay * EE + t];
            #pragma unroll 8
            for (int k = 0; k < EE; ++k)
                hn = fmaf(aggfin[k], ow[k * EE], hn);
            hsh[t] = hn;   // same thread read+write own element; others sync at loop top
        }
    }

    __syncthreads();
    if (t < EE) hout[(size_t)row * EE + t] = hsh[t];
}

__global__ __launch_bounds__(1024) void k_tail(
    const float* __restrict__ hbuf,        // B*N,128
    const int*   __restrict__ open_group,  // B,N
    const float* __restrict__ context_w,   // 128,128
    const float* __restrict__ key_w,       // 128,128
    const int*   __restrict__ action_mask, // B,N
    const float* __restrict__ logit_bias,  // 1
    float* __restrict__ out)               // B,N
{
    const int b = blockIdx.x;
    const int t = threadIdx.x;
    const int e = t & 127;
    const int s = t >> 7;                  // 0..7

    __shared__ float gmsh[8][EE];
    __shared__ float cntsh[8];
    __shared__ float csh[EE];
    __shared__ float qsh[EE];
    __shared__ float qksh[EE];

    const float* hb = hbuf + (size_t)b * NN * EE;

    // masked group-sum over n, 8-way split
    float gm = 0.0f, cnt = 0.0f;
    const int n0 = s * 64;
    #pragma unroll 4
    for (int u = 0; u < 64; ++u) {
        const int n = n0 + u;
        const float m = (float)open_group[b * NN + n];
        gm = fmaf(m, hb[(size_t)n * EE + e], gm);
        cnt += m;
    }
    gmsh[s][e] = gm;
    if (e == 0) cntsh[s] = cnt;
    __syncthreads();

    if (s == 0) {
        float ca = 0.0f, ga = 0.0f;
        #pragma unroll
        for (int u = 0; u < 8; ++u) { ca += cntsh[u]; ga += gmsh[u][e]; }
        csh[e] = (ca > 0.0f) ? (ga / fmaxf(ca, 1.0f)) : hb[e];  // hb[e]=h[b,0,e]
    }
    __syncthreads();

    if (s == 0) {
        float q = 0.0f;
        #pragma unroll 8
        for (int k = 0; k < EE; ++k)
            q = fmaf(csh[k], context_w[k * EE + e], q);
        qsh[e] = q;
    }
    __syncthreads();

    if (s == 0) {
        float acc = 0.0f;
        const float* kr = key_w + e * EE;   // qk[e] = key_w[e,:] . q
        #pragma unroll 8
        for (int k = 0; k < EE; ++k)
            acc = fmaf(kr[k], qsh[k], acc);
        qksh[e] = acc;
    }
    __syncthreads();

    // ---- logits: 16 waves x 32 rows each ----
    const int wid  = t >> 6;               // 0..15
    const int lane = t & 63;
    const float lb = logit_bias[0];

    for (int r = wid; r < NN; r += 16) {
        const float* hr = hb + (size_t)r * EE;
        float p = hr[lane] * qksh[lane] + hr[lane + 64] * qksh[lane + 64];
        #pragma unroll
        for (int off = 32; off; off >>= 1)
            p += __shfl_down(p, off);
        if (lane == 0) {
            float v = fmaf(p, 0.08838834764831845f, lb);   // /sqrt(128)
            out[b * NN + r] = action_mask[b * NN + r] ? v : -1000000000.0f;
        }
    }
}

extern "C" void kernel_launch(void* const* d_in, const int* in_sizes, int n_in,
                              void* d_out, int out_size, void* d_ws, size_t ws_size,
                              hipStream_t stream) {
    const float* nf         = (const float*)d_in[0];
    const float* ef         = (const float*)d_in[1];
    const float* W          = (const float*)d_in[2];
    const int*   assigned   = (const int*)d_in[3];
    const int*   open_group = (const int*)d_in[4];
    const int*   action_mask= (const int*)d_in[5];
    const float* build_limit= (const float*)d_in[6];
    const float* og_size    = (const float*)d_in[7];
    const float* embed_w    = (const float*)d_in[8];
    const float* embed_b    = (const float*)d_in[9];
    const float* node_w     = (const float*)d_in[10];
    const float* edge_w     = (const float*)d_in[11];
    const float* weight_w   = (const float*)d_in[12];
    const float* out_w      = (const float*)d_in[13];
    const float* out_b      = (const float*)d_in[14];
    const float* context_w  = (const float*)d_in[15];
    const float* key_w      = (const float*)d_in[16];
    const float* logit_bias = (const float*)d_in[17];

    float* hbuf = (float*)d_ws;                       // B*N*E floats = 1 MB

    dim3 grid_rows(NN, BB, 1);
    k_rows<<<grid_rows, 512, 0, stream>>>(nf, ef, W, assigned, open_group,
        action_mask, build_limit, og_size, embed_w, embed_b, node_w, edge_w,
        weight_w, out_w, out_b, hbuf);

    k_tail<<<BB, 1024, 0, stream>>>(hbuf, open_group, context_w, key_w,
        action_mask, logit_bias, (float*)d_out);
}